// Round 11
// baseline (172.016 us; speedup 1.0000x reference)
//
#include <hip/hip_runtime.h>

#define TID ((int)threadIdx.x)

constexpr int Bb  = 2;
constexpr int Cc  = 128;
constexpr int Nn  = 4096;   // H*W
constexpr int NHh = 8;
constexpr int DHd = 16;
constexpr int NSP = 4;      // KV splits
constexpr float GN_EPS_F = 1e-5f;
// softmax scale folded into q, in exp2 domain: dh^-0.5 * log2(e)
constexpr float QSCALE = 0.25f * 1.4426950408889634f;

typedef float  f32x4  __attribute__((ext_vector_type(4)));
typedef float  f32x16 __attribute__((ext_vector_type(16)));
typedef short  s16x8  __attribute__((ext_vector_type(8)));
typedef unsigned short u16x8 __attribute__((ext_vector_type(8)));
typedef uint   u32x4  __attribute__((ext_vector_type(4)));

#if __has_builtin(__builtin_amdgcn_exp2f)
#define EXP2(x) __builtin_amdgcn_exp2f(x)
#else
#define EXP2(x) exp2f(x)
#endif

// workspace layout (float-offset units)
constexpr size_t WS_PART = 0;                               // 256 blocks * 8 g * 2 = 4096 floats
constexpr size_t WS_LP   = 4096;                            // [sp][bh][n] = 4*16*4096 = 262144
constexpr size_t WS_AOP  = WS_LP + (size_t)NSP*16*Nn;       // bf16 [sp][b][n][c]: 4,194,304 ushorts
constexpr size_t WS_QBF  = WS_AOP + ((size_t)NSP*Bb*Nn*Cc)/2;
constexpr size_t BF_ELEMS = (size_t)Bb*NHh*Nn*DHd;          // 1,048,576 ushorts each
constexpr size_t WS_W    = WS_QBF + 3*(BF_ELEMS/2);         // 8 * 16384 ushorts (hi[4], lo[4])

__device__ __forceinline__ ushort f2bf(float f) {
    uint u = __builtin_bit_cast(uint, f);
    u += 0x7fffu + ((u >> 16) & 1u);      // RNE
    return (ushort)(u >> 16);
}
__device__ __forceinline__ float bf2f(ushort u) {
    return __builtin_bit_cast(float, ((uint)u) << 16);
}
__device__ __forceinline__ uint cvt_pk_bf16(float lo, float hi) {
    uint d;
    asm("v_cvt_pk_bf16_f32 %0, %1, %2" : "=v"(d) : "v"(lo), "v"(hi));
    return d;
}
// v_permlane32_swap_b32 a, b:  a <- [a_lo | b_lo], b <- [a_hi | b_hi]
__device__ __forceinline__ void pl32swap(uint& a, uint& b) {
    asm volatile("v_permlane32_swap_b32 %0, %1" : "+v"(a), "+v"(b));
}
__device__ __forceinline__ s16x8 pack4(uint a, uint b, uint c, uint d) {
    u32x4 u; u[0] = a; u[1] = b; u[2] = c; u[3] = d;
    return __builtin_bit_cast(s16x8, u);
}

// ---------------- weight prep: fp32 -> bf16 hi+lo pairs ----------------
__global__ __launch_bounds__(256) void prep_w_kernel(
    const float* __restrict__ Wq, const float* __restrict__ Wk,
    const float* __restrict__ Wv, const float* __restrict__ Wo,
    ushort* __restrict__ wh, ushort* __restrict__ wl)
{
    int id = blockIdx.x * 256 + TID;
    int which = id >> 14, i = id & 16383;
    const float* src = (which == 0) ? Wq : (which == 1) ? Wk : (which == 2) ? Wv : Wo;
    float v = src[i];
    if (which == 0) v *= QSCALE;
    ushort h = f2bf(v);
    ushort l = f2bf(v - bf2f(h));
    wh[id] = h;
    wl[id] = l;
}

// ---------------- QKV projection via MFMA (split-precision) ----------------
// grid: B * (N/32) = 256 blocks, 256 threads = 4 waves; wave w owns d-cols 32w..32w+31
__global__ __launch_bounds__(256) void qkv_kernel(
    const float* __restrict__ x,
    const float* __restrict__ bq, const float* __restrict__ bk, const float* __restrict__ bv,
    const ushort* __restrict__ wh, const ushort* __restrict__ wl,
    ushort* __restrict__ qbf, ushort* __restrict__ kbf, ushort* __restrict__ vtbf)
{
    const int b  = blockIdx.x >> 7;
    const int n0 = (blockIdx.x & 127) << 5;
    __shared__ __align__(16) ushort xh[32][136];
    __shared__ __align__(16) ushort xl[32][136];

    // stage x[b][c][n0..n0+32) -> transposed bf16 hi/lo [n][c]
    const float* xb = x + (size_t)b * Cc * Nn;
    {
        int c = TID >> 1, nh2 = (TID & 1) * 16;
#pragma unroll
        for (int j = 0; j < 4; ++j) {
            float4 v4 = *(const float4*)&xb[(size_t)c * Nn + n0 + nh2 + 4*j];
            float f[4] = {v4.x, v4.y, v4.z, v4.w};
#pragma unroll
            for (int e = 0; e < 4; ++e) {
                int n = nh2 + 4*j + e;
                ushort h = f2bf(f[e]);
                xh[n][c] = h;
                xl[n][c] = f2bf(f[e] - bf2f(h));
            }
        }
    }
    __syncthreads();

    const int lane = TID & 63, wave = TID >> 6;
    const int l31 = lane & 31, hi = lane >> 5;
    const int d0 = wave * 32;

    const ushort* wqh = wh;              const ushort* wql = wl;
    const ushort* wkh = wh + 16384;      const ushort* wkl = wl + 16384;
    const ushort* wvh = wh + 2 * 16384;  const ushort* wvl = wl + 2 * 16384;

    f32x16 qacc = (f32x16)(0.f), kacc = (f32x16)(0.f);
    f32x16 vacc = (f32x16)(bv[d0 + l31]);
    const size_t wrow = (size_t)(d0 + l31) * 128;

#pragma unroll 2
    for (int ks = 0; ks < 8; ++ks) {
        const int co = ks * 16 + 8 * hi;
        s16x8 xhf = *(const s16x8*)&xh[l31][co];
        s16x8 xlf = *(const s16x8*)&xl[l31][co];
        s16x8 aqh = *(const s16x8*)(wqh + wrow + co);
        s16x8 aql = *(const s16x8*)(wql + wrow + co);
        s16x8 akh = *(const s16x8*)(wkh + wrow + co);
        s16x8 akl = *(const s16x8*)(wkl + wrow + co);
        s16x8 avh = *(const s16x8*)(wvh + wrow + co);
        s16x8 avl = *(const s16x8*)(wvl + wrow + co);
        // Q,K: D[row=d][col=n] = W . x   (lane = n-col, regs = d-quads)
        qacc = __builtin_amdgcn_mfma_f32_32x32x16_bf16(aqh, xhf, qacc, 0, 0, 0);
        qacc = __builtin_amdgcn_mfma_f32_32x32x16_bf16(aql, xhf, qacc, 0, 0, 0);
        qacc = __builtin_amdgcn_mfma_f32_32x32x16_bf16(aqh, xlf, qacc, 0, 0, 0);
        kacc = __builtin_amdgcn_mfma_f32_32x32x16_bf16(akh, xhf, kacc, 0, 0, 0);
        kacc = __builtin_amdgcn_mfma_f32_32x32x16_bf16(akl, xhf, kacc, 0, 0, 0);
        kacc = __builtin_amdgcn_mfma_f32_32x32x16_bf16(akh, xlf, kacc, 0, 0, 0);
        // V: D[row=n][col=d] = x . Wv   (lane = d-col, regs = n-quads)
        vacc = __builtin_amdgcn_mfma_f32_32x32x16_bf16(xhf, avh, vacc, 0, 0, 0);
        vacc = __builtin_amdgcn_mfma_f32_32x32x16_bf16(xhf, avl, vacc, 0, 0, 0);
        vacc = __builtin_amdgcn_mfma_f32_32x32x16_bf16(xlf, avh, vacc, 0, 0, 0);
    }

    // ---- Q/K epilogue: lane = n-col; quad q -> d rows {d0+8q+4hi+0..3} ----
    {
        const int n = n0 + l31;
#pragma unroll
        for (int q = 0; q < 4; ++q) {
            const int dbase = d0 + 8*q + 4*hi;
            const int h = dbase >> 4, dh0 = dbase & 15;
            float4 bq4 = *(const float4*)&bq[dbase];
            float4 bk4 = *(const float4*)&bk[dbase];
            uint2 wq2, wk2;
            wq2.x = cvt_pk_bf16(qacc[4*q+0] + bq4.x * QSCALE, qacc[4*q+1] + bq4.y * QSCALE);
            wq2.y = cvt_pk_bf16(qacc[4*q+2] + bq4.z * QSCALE, qacc[4*q+3] + bq4.w * QSCALE);
            wk2.x = cvt_pk_bf16(kacc[4*q+0] + bk4.x, kacc[4*q+1] + bk4.y);
            wk2.y = cvt_pk_bf16(kacc[4*q+2] + bk4.z, kacc[4*q+3] + bk4.w);
            size_t base = ((size_t)((b*NHh + h) * Nn + n)) * DHd + dh0;
            *(uint2*)(qbf + base) = wq2;
            *(uint2*)(kbf + base) = wk2;
        }
    }
    // ---- V epilogue: lane = d-col; quad q -> n rows {n0+8q+4hi+0..3} ----
    {
        const int d = d0 + l31;
        const int h = d >> 4, dd = d & 15;
        ushort* vrow = vtbf + ((size_t)(b*NHh + h) * DHd + dd) * Nn;
#pragma unroll
        for (int q = 0; q < 4; ++q) {
            uint2 w2;
            w2.x = cvt_pk_bf16(vacc[4*q+0], vacc[4*q+1]);
            w2.y = cvt_pk_bf16(vacc[4*q+2], vacc[4*q+3]);
            *(uint2*)(vrow + n0 + 8*q + 4*hi) = w2;
        }
    }
}

// ---------------- Flash attention: zero-LDS, zero-barrier ----------------
// Swapped QK^T (32x32x16, P^T in regs) + permlane32_swap P redistribution +
// swapped PV -> O^T. K, V fragments read directly from global (L1-shared).
// grid: bh(16) * sp(4) * qt(32) = 2048 blocks, 256 threads = 4 waves, 32 q/wave
__global__ __launch_bounds__(256, 4) void attn_kernel(
    const ushort* __restrict__ qbf, const ushort* __restrict__ kbf,
    const ushort* __restrict__ vtbf, ushort* __restrict__ aop, float* __restrict__ lp)
{
    const int qt = blockIdx.x & 31;
    const int sp = (blockIdx.x >> 5) & 3;
    const int bh = blockIdx.x >> 7;
    const int q0 = qt << 7;
    const int kvbase = sp << 10;    // 1024 kv rows per split
    const ushort* qb  = qbf  + (size_t)bh * Nn * DHd;
    const ushort* kb  = kbf  + (size_t)bh * Nn * DHd;
    const ushort* vtb = vtbf + (size_t)bh * DHd * Nn;

    const int lane = TID & 63, wave = TID >> 6;
    const int l31 = lane & 31, hi = lane >> 5;
    const int wq = q0 + wave * 32;

    // Q as B-operand: lane holds Q[wq+l31][8hi..8hi+7]
    const s16x8 qfrag = *(const s16x8*)(qb + (size_t)(wq + l31) * DHd + 8 * hi);

    float l_run = 0.0f;
    f32x16 ot = (f32x16)(0.f);     // O^T: lane = q-col, regs 0..7 = d rows

    const ushort* vrow = vtb + (size_t)(l31 & 15) * Nn + 8 * hi;

    for (int kv0 = kvbase; kv0 < kvbase + 1024; kv0 += 64) {
        // ---- S^T = K . Q^T : A = K rows (direct global, coalesced 16B/lane) ----
        const ushort* krow = kb + (size_t)kv0 * DHd + 8 * hi;
        s16x8 af0 = *(const s16x8*)(krow + (size_t)l31 * DHd);
        s16x8 af1 = *(const s16x8*)(krow + (size_t)(l31 + 32) * DHd);
        f32x16 st0 = __builtin_amdgcn_mfma_f32_32x32x16_bf16(af0, qfrag, (f32x16)(0.f), 0, 0, 0);
        f32x16 st1 = __builtin_amdgcn_mfma_f32_32x32x16_bf16(af1, qfrag, (f32x16)(0.f), 0, 0, 0);

        // ---- p = exp2(s), pack to bf16 pairs in-register ----
        float rs = 0.f;
        uint p0,p1,p2,p3,p4,p5,p6,p7,p8,p9,p10,p11,p12,p13,p14,p15;
#define PKE(dst, sreg, i0, i1) { float e0 = EXP2(sreg[i0]); float e1 = EXP2(sreg[i1]); \
                                 rs += e0 + e1; dst = cvt_pk_bf16(e0, e1); }
        PKE(p0,  st0,  0,  1)  PKE(p1,  st0,  2,  3)
        PKE(p2,  st0,  4,  5)  PKE(p3,  st0,  6,  7)
        PKE(p4,  st0,  8,  9)  PKE(p5,  st0, 10, 11)
        PKE(p6,  st0, 12, 13)  PKE(p7,  st0, 14, 15)
        PKE(p8,  st1,  0,  1)  PKE(p9,  st1,  2,  3)
        PKE(p10, st1,  4,  5)  PKE(p11, st1,  6,  7)
        PKE(p12, st1,  8,  9)  PKE(p13, st1, 10, 11)
        PKE(p14, st1, 12, 13)  PKE(p15, st1, 14, 15)
#undef PKE
        // redistribute halves: after swap(a,b): a=[a_lo|b_lo], b=[a_hi|b_hi]
        pl32swap(p0,  p2);  pl32swap(p1,  p3);    // kv  0-15 frag = {p0,p1,p2,p3}
        pl32swap(p4,  p6);  pl32swap(p5,  p7);    // kv 16-31 frag = {p4,p5,p6,p7}
        pl32swap(p8,  p10); pl32swap(p9,  p11);   // kv 32-47
        pl32swap(p12, p14); pl32swap(p13, p15);   // kv 48-63

        // ---- O^T += V^T . P^T  (A = V^T rows, dup'd d 0..15; B = P frag) ----
        s16x8 vf0 = *(const s16x8*)(vrow + kv0);
        s16x8 vf1 = *(const s16x8*)(vrow + kv0 + 16);
        s16x8 vf2 = *(const s16x8*)(vrow + kv0 + 32);
        s16x8 vf3 = *(const s16x8*)(vrow + kv0 + 48);
        ot = __builtin_amdgcn_mfma_f32_32x32x16_bf16(vf0, pack4(p0,p1,p2,p3),     ot, 0, 0, 0);
        ot = __builtin_amdgcn_mfma_f32_32x32x16_bf16(vf1, pack4(p4,p5,p6,p7),     ot, 0, 0, 0);
        ot = __builtin_amdgcn_mfma_f32_32x32x16_bf16(vf2, pack4(p8,p9,p10,p11),   ot, 0, 0, 0);
        ot = __builtin_amdgcn_mfma_f32_32x32x16_bf16(vf3, pack4(p12,p13,p14,p15), ot, 0, 0, 0);

        l_run += rs;
    }

    // epilogue: write UNNORMALIZED O^T (bf16) + per-q partial l
    l_run += __shfl_xor(l_run, 32, 64);
    if (hi == 0)
        lp[((size_t)(sp * 16 + bh)) * Nn + wq + l31] = l_run;

    const int b = bh >> 3, hh = bh & 7;
    // lane = q-col; regs 0-3 = d {4hi+0..3}, regs 4-7 = d {8+4hi+0..3}
    ushort* ap = aop + (((size_t)(sp * Bb + b)) * Nn + wq + l31) * Cc + hh * DHd;
    uint2 w0, w1;
    w0.x = cvt_pk_bf16(ot[0], ot[1]); w0.y = cvt_pk_bf16(ot[2], ot[3]);
    w1.x = cvt_pk_bf16(ot[4], ot[5]); w1.y = cvt_pk_bf16(ot[6], ot[7]);
    *(uint2*)(ap + 4*hi)     = w0;
    *(uint2*)(ap + 8 + 4*hi) = w1;
}

// ---------------- split-combine + O projection (MFMA) + GN block partials ----------------
// grid: B * (N/32) = 256 blocks, 256 threads = 4 waves; wave w owns d-cols 32w..32w+31
__global__ __launch_bounds__(256) void oproj_kernel(
    const ushort* __restrict__ aop, const float* __restrict__ lp,
    const ushort* __restrict__ wh, const ushort* __restrict__ wl,
    const float* __restrict__ bo,
    float* __restrict__ y, float* __restrict__ partial)
{
    const int b  = blockIdx.x >> 7;
    const int nb = blockIdx.x & 127;
    const int n0 = nb << 5;
    __shared__ __align__(16) ushort aoc[32][136];
    __shared__ float linv[32][8];

    // per-(n,h) softmax denominators
    {
        int n = TID >> 3, h = TID & 7;
        float l = 0.f;
#pragma unroll
        for (int sp = 0; sp < NSP; ++sp)
            l += lp[((size_t)(sp * 16 + b * 8 + h)) * Nn + n0 + n];
        linv[n][h] = 1.0f / l;
    }
    __syncthreads();

    // combine splits -> normalized bf16 A-tile [32 n][128 c]
#pragma unroll
    for (int s = TID; s < 512; s += 256) {
        int n = s >> 4, c8 = s & 15;
        int c = c8 * 8;
        float a[8];
#pragma unroll
        for (int e = 0; e < 8; ++e) a[e] = 0.f;
#pragma unroll
        for (int sp = 0; sp < NSP; ++sp) {
            u16x8 u = *(const u16x8*)(aop + (((size_t)(sp * Bb + b)) * Nn + n0 + n) * Cc + c);
#pragma unroll
            for (int e = 0; e < 8; ++e) a[e] += bf2f(u[e]);
        }
        float li = linv[n][c >> 4];
        uint4 w;
        w.x = cvt_pk_bf16(a[0]*li, a[1]*li);
        w.y = cvt_pk_bf16(a[2]*li, a[3]*li);
        w.z = cvt_pk_bf16(a[4]*li, a[5]*li);
        w.w = cvt_pk_bf16(a[6]*li, a[7]*li);
        *(uint4*)&aoc[n][c] = w;
    }
    __syncthreads();

    const int lane = TID & 63, wave = TID >> 6;
    const int l31 = lane & 31, hi = lane >> 5;
    const int d0 = wave * 32;
    const ushort* woh = wh + 3 * 16384;
    const ushort* wol = wl + 3 * 16384;
    const size_t wrow = (size_t)(d0 + l31) * 128;

    f32x16 acc = (f32x16)(bo[d0 + l31]);
#pragma unroll
    for (int ks = 0; ks < 8; ++ks) {
        const int co = ks * 16 + 8 * hi;
        s16x8 aof = *(const s16x8*)&aoc[l31][co];
        s16x8 bh8 = *(const s16x8*)(woh + wrow + co);
        s16x8 bl8 = *(const s16x8*)(wol + wrow + co);
        // D[row=n][col=d] = ao . Wo  (lane = d-col, regs = n-quads)
        acc = __builtin_amdgcn_mfma_f32_32x32x16_bf16(aof, bh8, acc, 0, 0, 0);
        acc = __builtin_amdgcn_mfma_f32_32x32x16_bf16(aof, bl8, acc, 0, 0, 0);
    }

    // epilogue: y[b][d][n] float4 stores + GN partial sums
    const int d = d0 + l31;
    float* yrow = y + ((size_t)(b * Cc + d)) * Nn + n0;
    float s1 = 0.f, s2 = 0.f;
#pragma unroll
    for (int q = 0; q < 4; ++q) {
        float4 v4 = make_float4(acc[4*q+0], acc[4*q+1], acc[4*q+2], acc[4*q+3]);
        s1 += v4.x + v4.y + v4.z + v4.w;
        s2 += v4.x*v4.x + v4.y*v4.y + v4.z*v4.z + v4.w*v4.w;
        *(float4*)(yrow + 8*q + 4*hi) = v4;
    }
#pragma unroll
    for (int off = 1; off < 16; off <<= 1) {
        s1 += __shfl_xor(s1, off, 64);
        s2 += __shfl_xor(s2, off, 64);
    }
    s1 += __shfl_xor(s1, 32, 64);
    s2 += __shfl_xor(s2, 32, 64);
    if ((lane & 15) == 0 && hi == 0) {
        int g = d >> 4;
        float* p = partial + (((size_t)(b * 128 + nb)) * 8 + g) * 2;
        p[0] = s1; p[1] = s2;
    }
}

// ---------------- GN finalize: reduce 128 block-partials + affine + residual ----------------
__global__ __launch_bounds__(256) void finalize_kernel(
    const float* __restrict__ x, const float* __restrict__ gn_w, const float* __restrict__ gn_b,
    const float* __restrict__ partial, float* __restrict__ out)
{
    __shared__ float red[4][2];
    const size_t i0 = (size_t)blockIdx.x << 10;
    const int b = (int)(i0 >> 19);
    const int c = (int)((i0 >> 12) & 127);
    const int g = c >> 4;

    float s1 = 0.f, s2 = 0.f;
    if (TID < 128) {
        const float* p = partial + (((size_t)(b * 128 + TID)) * 8 + g) * 2;
        s1 = p[0]; s2 = p[1];
    }
#pragma unroll
    for (int off = 1; off < 64; off <<= 1) {
        s1 += __shfl_xor(s1, off, 64);
        s2 += __shfl_xor(s2, off, 64);
    }
    if ((TID & 63) == 0) { red[TID >> 6][0] = s1; red[TID >> 6][1] = s2; }
    __syncthreads();
    s1 = red[0][0] + red[1][0] + red[2][0] + red[3][0];
    s2 = red[0][1] + red[1][1] + red[2][1] + red[3][1];

    const float inv_cnt = 1.0f / 65536.0f;   // 16 ch * 4096 px per group
    float mean = s1 * inv_cnt;
    float var  = s2 * inv_cnt - mean * mean;
    float rstd = rsqrtf(var + GN_EPS_F);
    float a   = rstd * gn_w[c];
    float bb2 = gn_b[c] - mean * a;

    size_t i = i0 + (size_t)TID * 4;
    float4 yv = *(float4*)(out + i);
    float4 xv = *(const float4*)(x + i);
    float4 o;
    o.x = yv.x * a + bb2 + xv.x;
    o.y = yv.y * a + bb2 + xv.y;
    o.z = yv.z * a + bb2 + xv.z;
    o.w = yv.w * a + bb2 + xv.w;
    *(float4*)(out + i) = o;
}

extern "C" void kernel_launch(void* const* d_in, const int* in_sizes, int n_in,
                              void* d_out, int out_size, void* d_ws, size_t ws_size,
                              hipStream_t stream) {
    const float* x  = (const float*)d_in[0];
    const float* Wq = (const float*)d_in[1];
    const float* bq = (const float*)d_in[2];
    const float* Wk = (const float*)d_in[3];
    const float* bk = (const float*)d_in[4];
    const float* Wv = (const float*)d_in[5];
    const float* bv = (const float*)d_in[6];
    const float* Wo = (const float*)d_in[7];
    const float* bo = (const float*)d_in[8];
    const float* gw = (const float*)d_in[9];
    const float* gb = (const float*)d_in[10];
    float* out = (float*)d_out;
    float* ws  = (float*)d_ws;

    float*  partial = ws + WS_PART;
    float*  lpart   = ws + WS_LP;
    ushort* aop     = (ushort*)(ws + WS_AOP);
    ushort* qbf     = (ushort*)(ws + WS_QBF);
    ushort* kbf     = qbf + BF_ELEMS;
    ushort* vtbf    = kbf + BF_ELEMS;
    ushort* wh      = (ushort*)(ws + WS_W);
    ushort* wl      = wh + 4 * 16384;

    hipLaunchKernelGGL(prep_w_kernel, dim3(256), dim3(256), 0, stream,
                       Wq, Wk, Wv, Wo, wh, wl);
    hipLaunchKernelGGL(qkv_kernel, dim3(Bb * (Nn / 32)), dim3(256), 0, stream,
                       x, bq, bk, bv, wh, wl, qbf, kbf, vtbf);
    hipLaunchKernelGGL(attn_kernel, dim3(16 * NSP * 32), dim3(256), 0, stream,
                       qbf, kbf, vtbf, aop, lpart);
    hipLaunchKernelGGL(oproj_kernel, dim3(Bb * (Nn / 32)), dim3(256), 0, stream,
                       aop, lpart, wh, wl, bo, out, partial);
    hipLaunchKernelGGL(finalize_kernel, dim3((Bb * Cc * Nn) / 1024), dim3(256), 0, stream,
                       x, gw, gb, partial, out);
}